// Round 7
// baseline (512.061 us; speedup 1.0000x reference)
//
#include <hip/hip_runtime.h>

// x: (64,3,512,512) fp32 -> conv3x3 VALID + avgpool2x2 + sigmoid + per-batch sum.
// Fused stride-2 4x4 conv: w_eff[ky][kx] = 0.25*sum_{py,px in {0,1}} w[ky-py][kx-px].
//
// R6 = R2 (best dispatch, 140 us) + 3 fixes:
//  - SROWS=1: 32640 waves (~8/SIMD) for pure-TLP latency hiding (no row reuse existed)
//  - oc processed in PAIRS: 4 independent packed acc chains (R2 had 1 serial chain)
//  - kx-paired v2f math -> v_pk_fma_f32-friendly: operands are adjacent reg pairs
// R5 lesson (ord-69: same 356 us at 0.2 MB HBM traffic): we are issue/stall-bound,
// not memory-bound -- so TLP + fewer stalls per FMA is the lever.

#define IC 3
#define OCH 16
#define HH 512
#define WW 512

typedef float v2f __attribute__((ext_vector_type(2)));

__device__ __forceinline__ float fast_sigmoid(float v) {
    float e = __expf(-v);                    // v_exp_f32
    return __builtin_amdgcn_rcpf(1.0f + e);  // v_rcp_f32
}

// d_ws layout (R2's): per oc, 64 floats: [48 w_eff (idx ic*16+ky*4+kx)][bias][pad]
__global__ void build_weff(const float* __restrict__ w,
                           const float* __restrict__ bias,
                           float* __restrict__ ws)
{
    const int i = threadIdx.x;
    for (int idx = i; idx < OCH * 48; idx += 256) {
        int oc = idx / 48;
        int rem = idx - oc * 48;
        int ic = rem >> 4;
        int ky = (rem >> 2) & 3;
        int kx = rem & 3;
        float s = 0.f;
#pragma unroll
        for (int py = 0; py < 2; ++py) {
            int r = ky - py;
            if (r < 0 || r > 2) continue;
#pragma unroll
            for (int px = 0; px < 2; ++px) {
                int c = kx - px;
                if (c < 0 || c > 2) continue;
                s += w[((oc * IC + ic) * 3 + r) * 3 + c];
            }
        }
        ws[oc * 64 + rem] = 0.25f * s;
    }
    if (i < OCH) ws[i * 64 + 48] = bias[i];
}

__global__ __launch_bounds__(128)
void conv_pool_sig_sum(const float* __restrict__ x,
                       const float* __restrict__ wws,
                       float* __restrict__ out)
{
    const int tid = threadIdx.x;      // 0..127 == pooled-col-pair index
    const bool v1 = (tid < 127);      // pooled col 255 doesn't exist
    const int c0 = 4 * tid;           // input col base (max 508, 16B aligned)
    const int b = blockIdx.y;
    const int hp = blockIdx.x;        // one pooled row per block (SROWS=1)
    const int tail = v1 ? 4 : 0;      // right edge: re-read in-bounds, masked

    const float* xb = x + ((size_t)b * IC * HH + (size_t)2 * hp) * WW + c0;

    // Full 4x6 window, all ic: 72 floats, loaded once, consumed in order.
    float4 xa[IC][4];
    float2 xt[IC][4];
#pragma unroll
    for (int ic = 0; ic < IC; ++ic) {
        const float* pr = xb + (size_t)ic * HH * WW;
#pragma unroll
        for (int r = 0; r < 4; ++r) {
            xa[ic][r] = *(const float4*)(pr + r * WW);
            xt[ic][r] = *(const float2*)(pr + r * WW + tail);
        }
    }

    float lsA = 0.f, lsB = 0.f;

    // oc pairs: 4 independent packed acc chains; one batched s_load group per pair.
#pragma unroll 1
    for (int ocp = 0; ocp < OCH / 2; ++ocp) {
        const float* w0 = wws + (2 * ocp + 0) * 64;  // uniform -> s_load_dwordx16
        const float* w1 = wws + (2 * ocp + 1) * 64;

        // acc halves hold kx{0,1} and kx{2,3} partial sums; bias in .x once.
        v2f aA0 = {w0[48], 0.f}, aB0 = {w0[48], 0.f};
        v2f aA1 = {w1[48], 0.f}, aB1 = {w1[48], 0.f};

#pragma unroll
        for (int icr = 0; icr < IC * 4; ++icr) {
            const int ic = icr >> 2, r = icr & 3;
            const float4 a = xa[ic][r];
            const float2 t = xt[ic][r];
            const v2f xp01 = {a.x, a.y};   // adjacent regs (float4 lanes 0,1)
            const v2f xp23 = {a.z, a.w};   // adjacent regs (float4 lanes 2,3)
            const v2f xp45 = {t.x, t.y};   // adjacent regs (float2)
            const v2f wa01 = *(const v2f*)(w0 + icr * 4);      // {w0,w1} oc0
            const v2f wa23 = *(const v2f*)(w0 + icr * 4 + 2);  // {w2,w3} oc0
            const v2f wb01 = *(const v2f*)(w1 + icr * 4);      // {w0,w1} oc1
            const v2f wb23 = *(const v2f*)(w1 + icr * 4 + 2);  // {w2,w3} oc1
            aA0 += xp01 * wa01;  aA0 += xp23 * wa23;   // colA, oc0
            aB0 += xp23 * wa01;  aB0 += xp45 * wa23;   // colB, oc0
            aA1 += xp01 * wb01;  aA1 += xp23 * wb23;   // colA, oc1
            aB1 += xp23 * wb01;  aB1 += xp45 * wb23;   // colB, oc1
        }

        lsA += fast_sigmoid(aA0.x + aA0.y);
        lsB += fast_sigmoid(aB0.x + aB0.y);
        lsA += fast_sigmoid(aA1.x + aA1.y);
        lsB += fast_sigmoid(aB1.x + aB1.y);
    }
    lsA += v1 ? lsB : 0.f;

    // wave64 butterfly, one atomic per wave (2 per block)
#pragma unroll
    for (int off = 32; off > 0; off >>= 1)
        lsA += __shfl_xor(lsA, off, 64);
    if ((tid & 63) == 0) atomicAdd(out + b, lsA);
}

extern "C" void kernel_launch(void* const* d_in, const int* in_sizes, int n_in,
                              void* d_out, int out_size, void* d_ws, size_t ws_size,
                              hipStream_t stream) {
    const float* x = (const float*)d_in[0];
    const float* w = (const float*)d_in[1];
    const float* bias = (const float*)d_in[2];
    float* out = (float*)d_out;
    float* wws = (float*)d_ws;  // 16 * 64 floats = 4 KB

    hipMemsetAsync(out, 0, out_size * sizeof(float), stream);
    build_weff<<<1, 256, 0, stream>>>(w, bias, wws);

    dim3 grid(255, 64);  // one pooled row per block: 16320 blocks, ~8 waves/SIMD
    conv_pool_sig_sum<<<grid, 128, 0, stream>>>(x, wws, out);
}